// Round 5
// baseline (2871.930 us; speedup 1.0000x reference)
//
#include <hip/hip_runtime.h>
#include <hip/hip_cooperative_groups.h>

namespace cg = cooperative_groups;

#define NBUS 118
#define BATCH 4096
#define NN (BATCH * NBUS)          // 483328 nodes
#define END_E (4 * NN)             // 1933312 no-diag edges
#define EF_E (END_E + NN)          // 2416640 full edges
#define NLAYERS 10

#define SPAN 472                   // fine dst bucket span = 4*NBUS (batch-aligned)
#define NFB 1024                   // 1024*472 == NN exactly
#define TILE 4096                  // edges per binA block
#define ND_TILES (END_E / TILE)    // 472 (exact)
#define F_TILES  (EF_E / TILE)     // 590 (exact)
#define CAP_ND 2304                // staging cap: mean 1888, +9.5 sigma
#define CAP_F  2816                // staging cap: mean 2360, +9.4 sigma
#define LCAP_ND 2112               // LDS cap: mean +5.1 sigma (overflow -> global path)
#define LCAP_F  2560               // LDS cap: mean +4.1 sigma

#define NERR 64                    // spread error-atomic slots (stride 16 floats = 64B)

__device__ __forceinline__ float wf(int bits) { return __int_as_float(bits); }

// ---------- K1: p, denomInv, cursors, err partials ----------
__global__ void init_kernel(const float* __restrict__ x,
                            const float* __restrict__ ybus,
                            float* __restrict__ p,
                            float* __restrict__ denomInv,
                            int* __restrict__ cursor_nd,
                            int* __restrict__ cursor_f,
                            float* __restrict__ errPartial) {
    int tid = blockIdx.x * blockDim.x + threadIdx.x;
    int stride = gridDim.x * blockDim.x;
    for (int i = tid; i < NN; i += stride) {
        float2 xi = ((const float2*)x)[i];
        p[i] = xi.x - xi.y;
        int b = i / NBUS;
        int j = i - b * NBUS;
        denomInv[i] = 1.0f / (ybus[b * (NBUS * NBUS) + j * (NBUS + 1)] * 100.0f);
    }
    for (int i = tid; i < (NLAYERS + 1) * NERR * 16; i += stride) errPartial[i] = 0.0f;
    if (tid < NFB) {
        cursor_nd[tid] = tid * CAP_ND;
        cursor_f[tid]  = tid * CAP_F;
    }
}

// ---------- K2 (binA): tile -> LDS bin by fine bucket (span 472) -> staging ----------
// staged entry: .x = src | (dstLocal<<19)  (src < 2^19, dl < 472), .y = bits(w*100)
__global__ __launch_bounds__(256) void binA_kernel(
        const int* __restrict__ src_nd, const int* __restrict__ dst_nd,
        const float* __restrict__ ea_nd,
        const int* __restrict__ src_f, const int* __restrict__ dst_f,
        const float* __restrict__ ea_f,
        int* __restrict__ cursor_nd, int* __restrict__ cursor_f,
        uint2* __restrict__ stg_nd, uint2* __restrict__ stg_f) {
    __shared__ uint2 buf[TILE];              // 32 KB
    __shared__ unsigned short sb[TILE];      // 8 KB
    __shared__ int hist[NFB];                // 4 KB: counts, then write-cursor
    __shared__ int delta[NFB];               // 4 KB
    __shared__ int tsum[256];                // 1 KB

    bool isF = blockIdx.x >= ND_TILES;
    int tile = isF ? (blockIdx.x - ND_TILES) : blockIdx.x;
    const int* src = isF ? src_f : src_nd;
    const int* dst = isF ? dst_f : dst_nd;
    const float* ea = isF ? ea_f : ea_nd;
    int* cursor = isF ? cursor_f : cursor_nd;
    uint2* stg = isF ? stg_f : stg_nd;
    int cap = isF ? CAP_F : CAP_ND;

    int tid = threadIdx.x;
    int base = tile * TILE;

    #pragma unroll
    for (int k = 0; k < NFB / 256; ++k) hist[k * 256 + tid] = 0;
    __syncthreads();

    #pragma unroll
    for (int k = 0; k < TILE / 256; ++k) {
        unsigned d = (unsigned)dst[base + k * 256 + tid];
        atomicAdd(&hist[d / SPAN], 1);
    }
    __syncthreads();

    int c0 = hist[tid * 4 + 0], c1 = hist[tid * 4 + 1];
    int c2 = hist[tid * 4 + 2], c3 = hist[tid * 4 + 3];
    int s = c0 + c1 + c2 + c3;
    tsum[tid] = s;
    __syncthreads();
    for (int off = 1; off < 256; off <<= 1) {
        int t = (tid >= off) ? tsum[tid - off] : 0;
        __syncthreads();
        tsum[tid] += t;
        __syncthreads();
    }
    int basex = tsum[tid] - s;
    {
        int st[4];
        st[0] = basex; st[1] = basex + c0; st[2] = st[1] + c1; st[3] = st[2] + c2;
        int cc[4] = {c0, c1, c2, c3};
        #pragma unroll
        for (int k = 0; k < 4; ++k) {
            int bkt = tid * 4 + k;
            hist[bkt] = st[k];
            if (cc[k] > 0) {
                int gb = atomicAdd(&cursor[bkt], cc[k]);
                delta[bkt] = gb - st[k];
            }
        }
    }
    __syncthreads();

    #pragma unroll
    for (int k = 0; k < TILE / 256; ++k) {
        int e = base + k * 256 + tid;
        unsigned d = (unsigned)dst[e];
        unsigned bkt = d / SPAN;
        int pos = atomicAdd(&hist[bkt], 1);
        unsigned dl = d - bkt * SPAN;
        buf[pos] = make_uint2((unsigned)src[e] | (dl << 19),
                              (unsigned)__float_as_int(ea[e] * 100.0f));
        sb[pos] = (unsigned short)bkt;
    }
    __syncthreads();

    #pragma unroll
    for (int k = 0; k < TILE / 256; ++k) {
        int slot = k * 256 + tid;
        int bkt = sb[slot];
        int gpos = delta[bkt] + slot;
        if (gpos < (bkt + 1) * cap)  // freak-overflow guard
            stg[gpos] = buf[slot];
    }
}

// ---------- K3: persistent cooperative kernel: stage edges in LDS, run all epochs ----------
// Block = one 472-node bucket (= exactly 4 batches). Edges live in LDS for all
// 11 epochs. Edge-parallel inner loops (unroll x4 -> 4 gathers in flight/wave)
// accumulate per-node sums via LDS float atomics. Slack fused via zbuf.
// grid.sync() between epochs replaces per-layer dispatches.
__global__ __launch_bounds__(256, 4) void persist_kernel(
        const uint2* __restrict__ stg_nd, const uint2* __restrict__ stg_f,
        const int* __restrict__ cursor_nd, const int* __restrict__ cursor_f,
        const float* __restrict__ p, const float* __restrict__ denomInv,
        float* __restrict__ outA, float* __restrict__ outB,
        float* __restrict__ outF,
        float* __restrict__ errPartial) {
    __shared__ uint2 eF[LCAP_F];    // 20480 B
    __shared__ uint2 eN[LCAP_ND];   // 16896 B
    __shared__ float zbuf[SPAN];    //  1888 B
    __shared__ float ws[4];
    // total ~39.3 KB -> 4 blocks/CU (160 KB LDS), 16 waves/CU

    cg::grid_group grid = cg::this_grid();
    int tid = threadIdx.x;
    int fb = blockIdx.x;
    int gbase = fb * SPAN;

    int totF = cursor_f[fb] - fb * CAP_F;   if (totF > CAP_F) totF = CAP_F;
    int totN = cursor_nd[fb] - fb * CAP_ND; if (totN > CAP_ND) totN = CAP_ND;
    int limF = totF < LCAP_F ? totF : LCAP_F;
    int limN = totN < LCAP_ND ? totN : LCAP_ND;
    const uint2* sgF = stg_f + (long)fb * CAP_F;
    const uint2* sgN = stg_nd + (long)fb * CAP_ND;

    for (int i = tid; i < limF; i += 256) eF[i] = sgF[i];
    for (int i = tid; i < limN; i += 256) eN[i] = sgN[i];

    // per-thread nodes: n0 = tid (always), n1 = tid+256 (216 threads)
    int n0 = tid, n1 = tid + 256;
    bool a1 = (n1 < SPAN);
    float p0 = p[gbase + n0];
    float d0 = denomInv[gbase + n0];
    float p1 = a1 ? p[gbase + n1] : 0.0f;
    float d1 = a1 ? denomInv[gbase + n1] : 0.0f;
    int r0 = (n0 / NBUS) * NBUS;
    int r1 = (n1 / NBUS) * NBUS;

    // ---- epoch 0: out0 = p*di - slack (theta = 0, no gathers) ----
    zbuf[n0] = p0 * d0;
    if (a1) zbuf[n1] = p1 * d1;
    __syncthreads();
    outA[gbase + n0] = zbuf[n0] - zbuf[r0];
    if (a1) outA[gbase + n1] = zbuf[n1] - zbuf[r1];
    __threadfence();
    grid.sync();

    const float* cur = outA;
    for (int k = 1; k <= NLAYERS + 1; ++k) {
        // ======== F phase: err_{k-1} = sum |p - aggr_F(cur)| ========
        zbuf[n0] = 0.0f;
        if (a1) zbuf[n1] = 0.0f;
        __syncthreads();
        {
            int i = tid;
            for (; i + 768 < limF; i += 1024) {
                uint2 a = eF[i], b = eF[i + 256], c = eF[i + 512], d = eF[i + 768];
                float ga = cur[a.x & 0x7FFFF];
                float gb = cur[b.x & 0x7FFFF];
                float gc = cur[c.x & 0x7FFFF];
                float gd = cur[d.x & 0x7FFFF];
                atomicAdd(&zbuf[a.x >> 19], ga * wf(a.y));
                atomicAdd(&zbuf[b.x >> 19], gb * wf(b.y));
                atomicAdd(&zbuf[c.x >> 19], gc * wf(c.y));
                atomicAdd(&zbuf[d.x >> 19], gd * wf(d.y));
            }
            for (; i < limF; i += 256) {
                uint2 v = eF[i];
                atomicAdd(&zbuf[v.x >> 19], cur[v.x & 0x7FFFF] * wf(v.y));
            }
            for (i = limF + tid; i < totF; i += 256) {  // rare LDS-cap spill
                uint2 v = sgF[i];
                atomicAdd(&zbuf[v.x >> 19], cur[v.x & 0x7FFFF] * wf(v.y));
            }
        }
        __syncthreads();
        float acc = fabsf(p0 - zbuf[n0]) + (a1 ? fabsf(p1 - zbuf[n1]) : 0.0f);
        for (int off = 32; off > 0; off >>= 1) acc += __shfl_down(acc, off, 64);
        if ((tid & 63) == 0) ws[tid >> 6] = acc;
        __syncthreads();
        if (tid == 0)
            atomicAdd(&errPartial[(long)(k - 1) * NERR * 16 + (fb & (NERR - 1)) * 16],
                      ws[0] + ws[1] + ws[2] + ws[3]);
        if (k == NLAYERS + 1) break;

        // ======== ND phase: out_k = (p - aggr_ND(cur)) / denom - slack ========
        zbuf[n0] = 0.0f;
        if (a1) zbuf[n1] = 0.0f;
        __syncthreads();
        {
            int i = tid;
            for (; i + 768 < limN; i += 1024) {
                uint2 a = eN[i], b = eN[i + 256], c = eN[i + 512], d = eN[i + 768];
                float ga = cur[a.x & 0x7FFFF];
                float gb = cur[b.x & 0x7FFFF];
                float gc = cur[c.x & 0x7FFFF];
                float gd = cur[d.x & 0x7FFFF];
                atomicAdd(&zbuf[a.x >> 19], ga * wf(a.y));
                atomicAdd(&zbuf[b.x >> 19], gb * wf(b.y));
                atomicAdd(&zbuf[c.x >> 19], gc * wf(c.y));
                atomicAdd(&zbuf[d.x >> 19], gd * wf(d.y));
            }
            for (; i < limN; i += 256) {
                uint2 v = eN[i];
                atomicAdd(&zbuf[v.x >> 19], cur[v.x & 0x7FFFF] * wf(v.y));
            }
            for (i = limN + tid; i < totN; i += 256) {  // rare LDS-cap spill
                uint2 v = sgN[i];
                atomicAdd(&zbuf[v.x >> 19], cur[v.x & 0x7FFFF] * wf(v.y));
            }
        }
        __syncthreads();
        float z0 = (p0 - zbuf[n0]) * d0;
        float z1 = a1 ? (p1 - zbuf[n1]) * d1 : 0.0f;
        zbuf[n0] = z0;                 // own-slot overwrite, no cross-thread hazard
        if (a1) zbuf[n1] = z1;
        __syncthreads();
        float* dst = (k == NLAYERS) ? outF : ((k & 1) ? outB : outA);
        dst[gbase + n0] = zbuf[n0] - zbuf[r0];
        if (a1) dst[gbase + n1] = zbuf[n1] - zbuf[r1];
        __threadfence();
        grid.sync();
        cur = dst;
    }
}

// ---------- K6: reduce err partials -> errs[11] ----------
__global__ void err_reduce_kernel(const float* __restrict__ errPartial,
                                  float* __restrict__ errs) {
    int l = blockIdx.x;
    int t = threadIdx.x;  // 64
    float v = errPartial[l * (NERR * 16) + t * 16];
    for (int off = 32; off > 0; off >>= 1) v += __shfl_down(v, off, 64);
    if (t == 0) errs[l] = v;
}

extern "C" void kernel_launch(void* const* d_in, const int* in_sizes, int n_in,
                              void* d_out, int out_size, void* d_ws, size_t ws_size,
                              hipStream_t stream) {
    const float* x     = (const float*)d_in[0];
    const int*   ei_nd = (const int*)d_in[2];
    const float* ea_nd = (const float*)d_in[3];
    const int*   ei    = (const int*)d_in[4];
    const float* ea    = (const float*)d_in[5];
    const float* ybus  = (const float*)d_in[6];

    float* out_f = (float*)d_out;
    float* errs  = out_f + NN;

    // workspace carve (4-byte units)
    float* wsf        = (float*)d_ws;
    float* p          = wsf;          wsf += NN;
    float* denomInv   = wsf;          wsf += NN;
    float* outA       = wsf;          wsf += NN;
    float* outB       = wsf;          wsf += NN;
    int*   cursor_nd  = (int*)wsf;    wsf += NFB;
    int*   cursor_f   = (int*)wsf;    wsf += NFB;
    float* errPartial = wsf;          wsf += (NLAYERS + 1) * NERR * 16;  // 11264
    uint2* stg_nd     = (uint2*)wsf;  wsf += 2LL * NFB * CAP_ND;
    uint2* stg_f      = (uint2*)wsf;  wsf += 2LL * NFB * CAP_F;

    const int* src_nd = ei_nd;
    const int* dst_nd = ei_nd + END_E;
    const int* src_f  = ei;
    const int* dst_f  = ei + EF_E;

    // ---- build phase ----
    init_kernel<<<2048, 256, 0, stream>>>(x, ybus, p, denomInv,
                                          cursor_nd, cursor_f, errPartial);
    binA_kernel<<<ND_TILES + F_TILES, 256, 0, stream>>>(
        src_nd, dst_nd, ea_nd, src_f, dst_f, ea,
        cursor_nd, cursor_f, stg_nd, stg_f);

    // ---- iterate phase: one cooperative dispatch for all 11 epochs ----
    {
        void* args[] = {
            (void*)&stg_nd, (void*)&stg_f,
            (void*)&cursor_nd, (void*)&cursor_f,
            (void*)&p, (void*)&denomInv,
            (void*)&outA, (void*)&outB, (void*)&out_f,
            (void*)&errPartial
        };
        hipLaunchCooperativeKernel((void*)persist_kernel, dim3(NFB), dim3(256),
                                   args, 0, stream);
    }
    err_reduce_kernel<<<NLAYERS + 1, 64, 0, stream>>>(errPartial, errs);
}

// Round 6
// 834.679 us; speedup vs baseline: 3.4408x; 3.4408x over previous
//
#include <hip/hip_runtime.h>

#define NBUS 118
#define BATCH 4096
#define NN (BATCH * NBUS)          // 483328 nodes
#define END_E (4 * NN)             // 1933312 no-diag edges
#define EF_E (END_E + NN)          // 2416640 full edges
#define NLAYERS 10

#define SPAN 472                   // fine dst bucket span = 4*NBUS (batch-aligned)
#define NFB 1024                   // 1024*472 == NN exactly
#define TILE 4096                  // edges per binA block
#define ND_TILES (END_E / TILE)    // 472 (exact)
#define F_TILES  (EF_E / TILE)     // 590 (exact)
#define CAP_ND 2304                // staging cap: mean 1888, +9.5 sigma
#define CAP_F  2816                // staging cap: mean 2360, +9.4 sigma

#define NERR 64                    // spread error-atomic slots (stride 16 floats = 64B)

__device__ __forceinline__ float wf(int bits) { return __int_as_float(bits); }

// ---------- K1: p, denomInv, cursors, err partials ----------
__global__ void init_kernel(const float* __restrict__ x,
                            const float* __restrict__ ybus,
                            float* __restrict__ p,
                            float* __restrict__ denomInv,
                            int* __restrict__ cursor_nd,
                            int* __restrict__ cursor_f,
                            float* __restrict__ errPartial) {
    int tid = blockIdx.x * blockDim.x + threadIdx.x;
    int stride = gridDim.x * blockDim.x;
    for (int i = tid; i < NN; i += stride) {
        float2 xi = ((const float2*)x)[i];
        p[i] = xi.x - xi.y;
        int b = i / NBUS;
        int j = i - b * NBUS;
        denomInv[i] = 1.0f / (ybus[b * (NBUS * NBUS) + j * (NBUS + 1)] * 100.0f);
    }
    for (int i = tid; i < (NLAYERS + 1) * NERR * 16; i += stride) errPartial[i] = 0.0f;
    if (tid < NFB) {
        cursor_nd[tid] = tid * CAP_ND;
        cursor_f[tid]  = tid * CAP_F;
    }
}

// ---------- K2 (binA): tile -> LDS bin by fine bucket (span 472) -> staging ----------
// staged entry: .x = src | (dstLocal<<19)  (src < 2^19, dl < 472), .y = bits(w*100)
__global__ __launch_bounds__(256) void binA_kernel(
        const int* __restrict__ src_nd, const int* __restrict__ dst_nd,
        const float* __restrict__ ea_nd,
        const int* __restrict__ src_f, const int* __restrict__ dst_f,
        const float* __restrict__ ea_f,
        int* __restrict__ cursor_nd, int* __restrict__ cursor_f,
        uint2* __restrict__ stg_nd, uint2* __restrict__ stg_f) {
    __shared__ uint2 buf[TILE];              // 32 KB
    __shared__ unsigned short sb[TILE];      // 8 KB
    __shared__ int hist[NFB];                // 4 KB: counts, then write-cursor
    __shared__ int delta[NFB];               // 4 KB
    __shared__ int tsum[256];                // 1 KB

    bool isF = blockIdx.x >= ND_TILES;
    int tile = isF ? (blockIdx.x - ND_TILES) : blockIdx.x;
    const int* src = isF ? src_f : src_nd;
    const int* dst = isF ? dst_f : dst_nd;
    const float* ea = isF ? ea_f : ea_nd;
    int* cursor = isF ? cursor_f : cursor_nd;
    uint2* stg = isF ? stg_f : stg_nd;
    int cap = isF ? CAP_F : CAP_ND;

    int tid = threadIdx.x;
    int base = tile * TILE;

    #pragma unroll
    for (int k = 0; k < NFB / 256; ++k) hist[k * 256 + tid] = 0;
    __syncthreads();

    #pragma unroll
    for (int k = 0; k < TILE / 256; ++k) {
        unsigned d = (unsigned)dst[base + k * 256 + tid];
        atomicAdd(&hist[d / SPAN], 1);
    }
    __syncthreads();

    int c0 = hist[tid * 4 + 0], c1 = hist[tid * 4 + 1];
    int c2 = hist[tid * 4 + 2], c3 = hist[tid * 4 + 3];
    int s = c0 + c1 + c2 + c3;
    tsum[tid] = s;
    __syncthreads();
    for (int off = 1; off < 256; off <<= 1) {
        int t = (tid >= off) ? tsum[tid - off] : 0;
        __syncthreads();
        tsum[tid] += t;
        __syncthreads();
    }
    int basex = tsum[tid] - s;
    {
        int st[4];
        st[0] = basex; st[1] = basex + c0; st[2] = st[1] + c1; st[3] = st[2] + c2;
        int cc[4] = {c0, c1, c2, c3};
        #pragma unroll
        for (int k = 0; k < 4; ++k) {
            int bkt = tid * 4 + k;
            hist[bkt] = st[k];
            if (cc[k] > 0) {
                int gb = atomicAdd(&cursor[bkt], cc[k]);
                delta[bkt] = gb - st[k];
            }
        }
    }
    __syncthreads();

    #pragma unroll
    for (int k = 0; k < TILE / 256; ++k) {
        int e = base + k * 256 + tid;
        unsigned d = (unsigned)dst[e];
        unsigned bkt = d / SPAN;
        int pos = atomicAdd(&hist[bkt], 1);
        unsigned dl = d - bkt * SPAN;
        buf[pos] = make_uint2((unsigned)src[e] | (dl << 19),
                              (unsigned)__float_as_int(ea[e] * 100.0f));
        sb[pos] = (unsigned short)bkt;
    }
    __syncthreads();

    #pragma unroll
    for (int k = 0; k < TILE / 256; ++k) {
        int slot = k * 256 + tid;
        int bkt = sb[slot];
        int gpos = delta[bkt] + slot;
        if (gpos < (bkt + 1) * cap)  // freak-overflow guard
            stg[gpos] = buf[slot];
    }
}

// ---------- K3: layer 0 (theta = 0): out0 = p*denomInv - slack ----------
__global__ void out0_kernel(const float* __restrict__ p,
                            const float* __restrict__ denomInv,
                            float* __restrict__ out) {
    int b = blockIdx.x;
    int j = threadIdx.x;
    int i = b * NBUS + j;
    __shared__ float z0;
    float z = 0.0f;
    if (j < NBUS) z = p[i] * denomInv[i];
    if (j == 0) z0 = z;
    __syncthreads();
    if (j < NBUS) out[i] = z - z0;
}

// ---------- K4: edge-parallel fused layer ----------
// Block = one 472-node bucket. Each thread owns a static 6-record F slice and
// 5-record ND slice (sentinel (0,0) beyond count: weight 0 -> harmless add to
// slot 0). All ~11 gathers are issued before any use -> deep MLP. Sums land in
// LDS via ds_add_f32; the 472-lane combine fuses z, slack and the |err| reduce.
template <bool DO_OUT>
__global__ __launch_bounds__(512) void layer_kernel(
        const uint2* __restrict__ stg_nd, const uint2* __restrict__ stg_f,
        const int* __restrict__ cursor_nd, const int* __restrict__ cursor_f,
        const float* __restrict__ p, const float* __restrict__ denomInv,
        const float* __restrict__ cur,
        float* __restrict__ out,
        float* __restrict__ errPart /* NERR slots, stride 16 */) {
    __shared__ float zF[SPAN];
    __shared__ float zN[SPAN];
    __shared__ float ws[8];
    int tid = threadIdx.x;
    int fb = blockIdx.x;
    int gbase = fb * SPAN;

    if (tid < SPAN) { zF[tid] = 0.0f; zN[tid] = 0.0f; }
    __syncthreads();

    int totF = cursor_f[fb] - fb * CAP_F;   if (totF > CAP_F) totF = CAP_F;
    const uint2* sgF = stg_f + (long)fb * CAP_F;
    int totN = 0;
    const uint2* sgN = stg_nd + (long)fb * CAP_ND;
    if (DO_OUT) { totN = cursor_nd[fb] - fb * CAP_ND; if (totN > CAP_ND) totN = CAP_ND; }

    // --- phase A: load all edge records (coalesced), sentinel-padded ---
    uint2 rf0, rf1, rf2, rf3, rf4, rf5;
    uint2 rn0, rn1, rn2, rn3, rn4;
    rf0 = (tid          < totF) ? sgF[tid         ] : make_uint2(0u, 0u);
    rf1 = (tid +  512   < totF) ? sgF[tid +  512  ] : make_uint2(0u, 0u);
    rf2 = (tid + 1024   < totF) ? sgF[tid + 1024  ] : make_uint2(0u, 0u);
    rf3 = (tid + 1536   < totF) ? sgF[tid + 1536  ] : make_uint2(0u, 0u);
    rf4 = (tid + 2048   < totF) ? sgF[tid + 2048  ] : make_uint2(0u, 0u);
    rf5 = (tid + 2560   < totF) ? sgF[tid + 2560  ] : make_uint2(0u, 0u);
    if (DO_OUT) {
        rn0 = (tid        < totN) ? sgN[tid       ] : make_uint2(0u, 0u);
        rn1 = (tid +  512 < totN) ? sgN[tid +  512] : make_uint2(0u, 0u);
        rn2 = (tid + 1024 < totN) ? sgN[tid + 1024] : make_uint2(0u, 0u);
        rn3 = (tid + 1536 < totN) ? sgN[tid + 1536] : make_uint2(0u, 0u);
        rn4 = (tid + 2048 < totN) ? sgN[tid + 2048] : make_uint2(0u, 0u);
    }

    // --- phase B: issue all gathers (independent -> all in flight) ---
    float gf0 = cur[rf0.x & 0x7FFFF], gf1 = cur[rf1.x & 0x7FFFF];
    float gf2 = cur[rf2.x & 0x7FFFF], gf3 = cur[rf3.x & 0x7FFFF];
    float gf4 = cur[rf4.x & 0x7FFFF], gf5 = cur[rf5.x & 0x7FFFF];
    float gn0 = 0.0f, gn1 = 0.0f, gn2 = 0.0f, gn3 = 0.0f, gn4 = 0.0f;
    if (DO_OUT) {
        gn0 = cur[rn0.x & 0x7FFFF]; gn1 = cur[rn1.x & 0x7FFFF];
        gn2 = cur[rn2.x & 0x7FFFF]; gn3 = cur[rn3.x & 0x7FFFF];
        gn4 = cur[rn4.x & 0x7FFFF];
    }

    // --- phase C: LDS atomic accumulate (sentinels add 0.0 to slot 0) ---
    atomicAdd(&zF[rf0.x >> 19], gf0 * wf(rf0.y));
    atomicAdd(&zF[rf1.x >> 19], gf1 * wf(rf1.y));
    atomicAdd(&zF[rf2.x >> 19], gf2 * wf(rf2.y));
    atomicAdd(&zF[rf3.x >> 19], gf3 * wf(rf3.y));
    atomicAdd(&zF[rf4.x >> 19], gf4 * wf(rf4.y));
    atomicAdd(&zF[rf5.x >> 19], gf5 * wf(rf5.y));
    if (DO_OUT) {
        atomicAdd(&zN[rn0.x >> 19], gn0 * wf(rn0.y));
        atomicAdd(&zN[rn1.x >> 19], gn1 * wf(rn1.y));
        atomicAdd(&zN[rn2.x >> 19], gn2 * wf(rn2.y));
        atomicAdd(&zN[rn3.x >> 19], gn3 * wf(rn3.y));
        atomicAdd(&zN[rn4.x >> 19], gn4 * wf(rn4.y));
    }
    __syncthreads();

    // --- combine: err + z + fused slack ---
    float acc = 0.0f;
    if (tid < SPAN) {
        float pv = p[gbase + tid];
        acc = fabsf(pv - zF[tid]);
        if (DO_OUT) zN[tid] = (pv - zN[tid]) * denomInv[gbase + tid];
    }
    if (DO_OUT) {
        __syncthreads();
        if (tid < SPAN) out[gbase + tid] = zN[tid] - zN[(tid / NBUS) * NBUS];
    }
    for (int off = 32; off > 0; off >>= 1) acc += __shfl_down(acc, off, 64);
    if ((tid & 63) == 0) ws[tid >> 6] = acc;
    __syncthreads();
    if (tid == 0) {
        float t = 0.0f;
        #pragma unroll
        for (int w = 0; w < 8; ++w) t += ws[w];
        atomicAdd(&errPart[(fb & (NERR - 1)) * 16], t);
    }
}

// ---------- K5: reduce err partials -> errs[11] ----------
__global__ void err_reduce_kernel(const float* __restrict__ errPartial,
                                  float* __restrict__ errs) {
    int l = blockIdx.x;
    int t = threadIdx.x;  // 64
    float v = errPartial[l * (NERR * 16) + t * 16];
    for (int off = 32; off > 0; off >>= 1) v += __shfl_down(v, off, 64);
    if (t == 0) errs[l] = v;
}

extern "C" void kernel_launch(void* const* d_in, const int* in_sizes, int n_in,
                              void* d_out, int out_size, void* d_ws, size_t ws_size,
                              hipStream_t stream) {
    const float* x     = (const float*)d_in[0];
    const int*   ei_nd = (const int*)d_in[2];
    const float* ea_nd = (const float*)d_in[3];
    const int*   ei    = (const int*)d_in[4];
    const float* ea    = (const float*)d_in[5];
    const float* ybus  = (const float*)d_in[6];

    float* out_f = (float*)d_out;
    float* errs  = out_f + NN;

    // workspace carve (4-byte units)
    float* wsf        = (float*)d_ws;
    float* p          = wsf;          wsf += NN;
    float* denomInv   = wsf;          wsf += NN;
    float* outA       = wsf;          wsf += NN;
    float* outB       = wsf;          wsf += NN;
    int*   cursor_nd  = (int*)wsf;    wsf += NFB;
    int*   cursor_f   = (int*)wsf;    wsf += NFB;
    float* errPartial = wsf;          wsf += (NLAYERS + 1) * NERR * 16;  // 11264
    uint2* stg_nd     = (uint2*)wsf;  wsf += 2LL * NFB * CAP_ND;
    uint2* stg_f      = (uint2*)wsf;  wsf += 2LL * NFB * CAP_F;

    const int* src_nd = ei_nd;
    const int* dst_nd = ei_nd + END_E;
    const int* src_f  = ei;
    const int* dst_f  = ei + EF_E;

    // ---- build phase ----
    init_kernel<<<2048, 256, 0, stream>>>(x, ybus, p, denomInv,
                                          cursor_nd, cursor_f, errPartial);
    binA_kernel<<<ND_TILES + F_TILES, 256, 0, stream>>>(
        src_nd, dst_nd, ea_nd, src_f, dst_f, ea,
        cursor_nd, cursor_f, stg_nd, stg_f);

    // ---- iterate phase ----
    out0_kernel<<<BATCH, 128, 0, stream>>>(p, denomInv, outA);
    const float* cur = outA;
    for (int k = 1; k <= NLAYERS; ++k) {
        float* nxt = (k == NLAYERS) ? out_f : ((k & 1) ? outB : outA);
        layer_kernel<true><<<NFB, 512, 0, stream>>>(
            stg_nd, stg_f, cursor_nd, cursor_f, p, denomInv, cur, nxt,
            errPartial + (long)(k - 1) * NERR * 16);
        cur = nxt;
    }
    layer_kernel<false><<<NFB, 512, 0, stream>>>(
        stg_nd, stg_f, cursor_nd, cursor_f, p, denomInv, cur, nullptr,
        errPartial + (long)NLAYERS * NERR * 16);
    err_reduce_kernel<<<NLAYERS + 1, 64, 0, stream>>>(errPartial, errs);
}

// Round 7
// 801.370 us; speedup vs baseline: 3.5838x; 1.0416x over previous
//
#include <hip/hip_runtime.h>

#define NBUS 118
#define BATCH 4096
#define NN (BATCH * NBUS)          // 483328 nodes
#define END_E (4 * NN)             // 1933312 no-diag edges
#define EF_E (END_E + NN)          // 2416640 full edges
#define NLAYERS 10

#define SPAN 472                   // fine dst bucket span = 4*NBUS (batch-aligned)
#define NFB 1024                   // 1024*472 == NN exactly
#define CSPAN 1888                 // coarse span = 4*SPAN; 256*1888 == NN exactly
#define NCB 256                    // coarse buckets
#define TILE 4096                  // edges per binA block
#define ND_TILES (END_E / TILE)    // 472 (exact)
#define F_TILES  (EF_E / TILE)     // 590 (exact)
#define CAPC_ND 8192               // coarse cap: mean 7552, +7.4 sigma
#define CAPC_F  10240              // coarse cap: mean 9440, +8.2 sigma
#define CAP_ND 2304                // fine cap: mean 1888, +9.5 sigma
#define CAP_F  2816                // fine cap: mean 2360, +9.4 sigma

#define NERR 64                    // spread error-atomic slots (stride 16 floats = 64B)

__device__ __forceinline__ float wf(int bits) { return __int_as_float(bits); }

// ---------- K1: p, denomInv, coarse cursors, err partials ----------
__global__ void init_kernel(const float* __restrict__ x,
                            const float* __restrict__ ybus,
                            float* __restrict__ p,
                            float* __restrict__ denomInv,
                            int* __restrict__ cursorC_nd,
                            int* __restrict__ cursorC_f,
                            float* __restrict__ errPartial) {
    int tid = blockIdx.x * blockDim.x + threadIdx.x;
    int stride = gridDim.x * blockDim.x;
    for (int i = tid; i < NN; i += stride) {
        float2 xi = ((const float2*)x)[i];
        p[i] = xi.x - xi.y;
        int b = i / NBUS;
        int j = i - b * NBUS;
        denomInv[i] = 1.0f / (ybus[b * (NBUS * NBUS) + j * (NBUS + 1)] * 100.0f);
    }
    for (int i = tid; i < (NLAYERS + 1) * NERR * 16; i += stride) errPartial[i] = 0.0f;
    if (tid < NCB) {
        cursorC_nd[tid] = tid * CAPC_ND;
        cursorC_f[tid]  = tid * CAPC_F;
    }
}

// ---------- K2 (binA): tile -> LDS bin by COARSE bucket (span 1888) -> staging ----------
// staged entry: .x = src | (dlCoarse<<19)  (src < 2^19, dl < 1888 = 11 bits), .y = bits(w*100)
// 256 buckets -> ~16-entry (128B) runs per bucket per tile -> coalesced scatter (R0-proven).
__global__ __launch_bounds__(256) void binA_kernel(
        const int* __restrict__ src_nd, const int* __restrict__ dst_nd,
        const float* __restrict__ ea_nd,
        const int* __restrict__ src_f, const int* __restrict__ dst_f,
        const float* __restrict__ ea_f,
        int* __restrict__ cursorC_nd, int* __restrict__ cursorC_f,
        uint2* __restrict__ stgC_nd, uint2* __restrict__ stgC_f) {
    __shared__ uint2 buf[TILE];            // 32 KB
    __shared__ unsigned char sb[TILE];     // 4 KB
    __shared__ int hist[256];
    __shared__ int scanA[256];
    __shared__ int segStart[256];
    __shared__ int segGBase[256];

    bool isF = blockIdx.x >= ND_TILES;
    int tile = isF ? (blockIdx.x - ND_TILES) : blockIdx.x;
    const int* src = isF ? src_f : src_nd;
    const int* dst = isF ? dst_f : dst_nd;
    const float* ea = isF ? ea_f : ea_nd;
    int* cursor = isF ? cursorC_f : cursorC_nd;
    uint2* stg = isF ? stgC_f : stgC_nd;
    int cap = isF ? CAPC_F : CAPC_ND;

    int tid = threadIdx.x;
    int base = tile * TILE;

    hist[tid] = 0;
    __syncthreads();

    #pragma unroll
    for (int k = 0; k < TILE / 256; ++k) {
        unsigned d = (unsigned)dst[base + k * 256 + tid];
        atomicAdd(&hist[d / CSPAN], 1);
    }
    __syncthreads();

    int cnt = hist[tid];
    scanA[tid] = cnt;
    __syncthreads();
    for (int off = 1; off < 256; off <<= 1) {
        int t = (tid >= off) ? scanA[tid - off] : 0;
        __syncthreads();
        scanA[tid] += t;
        __syncthreads();
    }
    int excl = scanA[tid] - cnt;
    segStart[tid] = excl;
    hist[tid] = excl;
    if (cnt > 0) segGBase[tid] = atomicAdd(&cursor[tid], cnt);
    __syncthreads();

    #pragma unroll
    for (int k = 0; k < TILE / 256; ++k) {
        int e = base + k * 256 + tid;
        unsigned d = (unsigned)dst[e];
        unsigned bkt = d / CSPAN;
        int pos = atomicAdd(&hist[bkt], 1);
        unsigned dl = d - bkt * CSPAN;             // 11 bits
        buf[pos] = make_uint2((unsigned)src[e] | (dl << 19),
                              (unsigned)__float_as_int(ea[e] * 100.0f));
        sb[pos] = (unsigned char)bkt;
    }
    __syncthreads();

    #pragma unroll
    for (int k = 0; k < TILE / 256; ++k) {
        int slot = k * 256 + tid;
        int bkt = sb[slot];
        int gpos = segGBase[bkt] + (slot - segStart[bkt]);
        if (gpos < (bkt + 1) * cap)  // freak-overflow guard
            stg[gpos] = buf[slot];
    }
}

// ---------- K3 (binC): split coarse bucket -> 4 fine buckets (coalesced stream) ----------
// Block = one coarse bucket x {ND,F}. Wave-aggregated LDS cursors: one atomic
// per wave per fine-bucket -> ~16 consecutive positions per wave -> 128B write
// runs. Re-encodes dl: 11-bit coarse-local -> 9-bit fine-local. Edge order
// within a fine bucket is arbitrary (layer doesn't care).
__global__ __launch_bounds__(512) void binC_kernel(
        const uint2* __restrict__ stgC_nd, const uint2* __restrict__ stgC_f,
        const int* __restrict__ cursorC_nd, const int* __restrict__ cursorC_f,
        uint2* __restrict__ stg_nd, uint2* __restrict__ stg_f,
        int* __restrict__ cursor_nd, int* __restrict__ cursor_f) {
    __shared__ int lcur[4];
    bool isF = blockIdx.x >= NCB;
    int cb = isF ? (blockIdx.x - NCB) : blockIdx.x;
    int capC = isF ? CAPC_F : CAPC_ND;
    int capFine = isF ? CAP_F : CAP_ND;
    const uint2* in = (isF ? stgC_f : stgC_nd) + (long)cb * capC;
    uint2* out = isF ? stg_f : stg_nd;
    int* curOut = isF ? cursor_f : cursor_nd;
    int tot = (isF ? cursorC_f[cb] : cursorC_nd[cb]) - cb * capC;
    if (tot > capC) tot = capC;

    int tid = threadIdx.x;
    int lane = tid & 63;
    if (tid < 4) lcur[tid] = 0;
    __syncthreads();

    for (int i = tid; i < tot; i += 512) {
        uint2 v = in[i];
        unsigned dl11 = v.x >> 19;
        int f = (dl11 >= 3 * SPAN) ? 3 : (dl11 >= 2 * SPAN) ? 2 : (dl11 >= SPAN) ? 1 : 0;
        unsigned dl9 = dl11 - (unsigned)f * SPAN;
        // wave-aggregated cursor bump for this f group
        unsigned long long m0 = __ballot(f == 0);
        unsigned long long m1 = __ballot(f == 1);
        unsigned long long m2 = __ballot(f == 2);
        unsigned long long m3 = __ballot(f == 3);
        unsigned long long mf = (f == 0) ? m0 : (f == 1) ? m1 : (f == 2) ? m2 : m3;
        int leader = __ffsll((unsigned long long)mf) - 1;
        int rank = __popcll(mf & ((1ull << lane) - 1ull));
        int base = 0;
        if (lane == leader) base = atomicAdd(&lcur[f], (int)__popcll(mf));
        base = __shfl(base, leader, 64);
        int pos = base + rank;
        int fbG = cb * 4 + f;
        if (pos < capFine)
            out[(long)fbG * capFine + pos] =
                make_uint2((v.x & 0x7FFFFu) | (dl9 << 19), v.y);
    }
    __syncthreads();
    if (tid < 4) {
        int fbG = cb * 4 + tid;
        int c = lcur[tid] < capFine ? lcur[tid] : capFine;
        curOut[fbG] = fbG * capFine + c;
    }
}

// ---------- K4: layer 0 (theta = 0): out0 = p*denomInv - slack ----------
__global__ void out0_kernel(const float* __restrict__ p,
                            const float* __restrict__ denomInv,
                            float* __restrict__ out) {
    int b = blockIdx.x;
    int j = threadIdx.x;
    int i = b * NBUS + j;
    __shared__ float z0;
    float z = 0.0f;
    if (j < NBUS) z = p[i] * denomInv[i];
    if (j == 0) z0 = z;
    __syncthreads();
    if (j < NBUS) out[i] = z - z0;
}

// ---------- K5: edge-parallel fused layer (unchanged from R6; proven ~41 us) ----------
template <bool DO_OUT>
__global__ __launch_bounds__(512) void layer_kernel(
        const uint2* __restrict__ stg_nd, const uint2* __restrict__ stg_f,
        const int* __restrict__ cursor_nd, const int* __restrict__ cursor_f,
        const float* __restrict__ p, const float* __restrict__ denomInv,
        const float* __restrict__ cur,
        float* __restrict__ out,
        float* __restrict__ errPart /* NERR slots, stride 16 */) {
    __shared__ float zF[SPAN];
    __shared__ float zN[SPAN];
    __shared__ float ws[8];
    int tid = threadIdx.x;
    int fb = blockIdx.x;
    int gbase = fb * SPAN;

    if (tid < SPAN) { zF[tid] = 0.0f; zN[tid] = 0.0f; }
    __syncthreads();

    int totF = cursor_f[fb] - fb * CAP_F;   if (totF > CAP_F) totF = CAP_F;
    const uint2* sgF = stg_f + (long)fb * CAP_F;
    int totN = 0;
    const uint2* sgN = stg_nd + (long)fb * CAP_ND;
    if (DO_OUT) { totN = cursor_nd[fb] - fb * CAP_ND; if (totN > CAP_ND) totN = CAP_ND; }

    // --- phase A: load all edge records (coalesced), sentinel-padded ---
    uint2 rf0, rf1, rf2, rf3, rf4, rf5;
    uint2 rn0, rn1, rn2, rn3, rn4;
    rf0 = (tid          < totF) ? sgF[tid         ] : make_uint2(0u, 0u);
    rf1 = (tid +  512   < totF) ? sgF[tid +  512  ] : make_uint2(0u, 0u);
    rf2 = (tid + 1024   < totF) ? sgF[tid + 1024  ] : make_uint2(0u, 0u);
    rf3 = (tid + 1536   < totF) ? sgF[tid + 1536  ] : make_uint2(0u, 0u);
    rf4 = (tid + 2048   < totF) ? sgF[tid + 2048  ] : make_uint2(0u, 0u);
    rf5 = (tid + 2560   < totF) ? sgF[tid + 2560  ] : make_uint2(0u, 0u);
    if (DO_OUT) {
        rn0 = (tid        < totN) ? sgN[tid       ] : make_uint2(0u, 0u);
        rn1 = (tid +  512 < totN) ? sgN[tid +  512] : make_uint2(0u, 0u);
        rn2 = (tid + 1024 < totN) ? sgN[tid + 1024] : make_uint2(0u, 0u);
        rn3 = (tid + 1536 < totN) ? sgN[tid + 1536] : make_uint2(0u, 0u);
        rn4 = (tid + 2048 < totN) ? sgN[tid + 2048] : make_uint2(0u, 0u);
    }

    // --- phase B: issue all gathers (independent -> all in flight) ---
    float gf0 = cur[rf0.x & 0x7FFFF], gf1 = cur[rf1.x & 0x7FFFF];
    float gf2 = cur[rf2.x & 0x7FFFF], gf3 = cur[rf3.x & 0x7FFFF];
    float gf4 = cur[rf4.x & 0x7FFFF], gf5 = cur[rf5.x & 0x7FFFF];
    float gn0 = 0.0f, gn1 = 0.0f, gn2 = 0.0f, gn3 = 0.0f, gn4 = 0.0f;
    if (DO_OUT) {
        gn0 = cur[rn0.x & 0x7FFFF]; gn1 = cur[rn1.x & 0x7FFFF];
        gn2 = cur[rn2.x & 0x7FFFF]; gn3 = cur[rn3.x & 0x7FFFF];
        gn4 = cur[rn4.x & 0x7FFFF];
    }

    // --- phase C: LDS atomic accumulate (sentinels add 0.0 to slot 0) ---
    atomicAdd(&zF[rf0.x >> 19], gf0 * wf(rf0.y));
    atomicAdd(&zF[rf1.x >> 19], gf1 * wf(rf1.y));
    atomicAdd(&zF[rf2.x >> 19], gf2 * wf(rf2.y));
    atomicAdd(&zF[rf3.x >> 19], gf3 * wf(rf3.y));
    atomicAdd(&zF[rf4.x >> 19], gf4 * wf(rf4.y));
    atomicAdd(&zF[rf5.x >> 19], gf5 * wf(rf5.y));
    if (DO_OUT) {
        atomicAdd(&zN[rn0.x >> 19], gn0 * wf(rn0.y));
        atomicAdd(&zN[rn1.x >> 19], gn1 * wf(rn1.y));
        atomicAdd(&zN[rn2.x >> 19], gn2 * wf(rn2.y));
        atomicAdd(&zN[rn3.x >> 19], gn3 * wf(rn3.y));
        atomicAdd(&zN[rn4.x >> 19], gn4 * wf(rn4.y));
    }
    __syncthreads();

    // --- combine: err + z + fused slack ---
    float acc = 0.0f;
    if (tid < SPAN) {
        float pv = p[gbase + tid];
        acc = fabsf(pv - zF[tid]);
        if (DO_OUT) zN[tid] = (pv - zN[tid]) * denomInv[gbase + tid];
    }
    if (DO_OUT) {
        __syncthreads();
        if (tid < SPAN) out[gbase + tid] = zN[tid] - zN[(tid / NBUS) * NBUS];
    }
    for (int off = 32; off > 0; off >>= 1) acc += __shfl_down(acc, off, 64);
    if ((tid & 63) == 0) ws[tid >> 6] = acc;
    __syncthreads();
    if (tid == 0) {
        float t = 0.0f;
        #pragma unroll
        for (int w = 0; w < 8; ++w) t += ws[w];
        atomicAdd(&errPart[(fb & (NERR - 1)) * 16], t);
    }
}

// ---------- K6: reduce err partials -> errs[11] ----------
__global__ void err_reduce_kernel(const float* __restrict__ errPartial,
                                  float* __restrict__ errs) {
    int l = blockIdx.x;
    int t = threadIdx.x;  // 64
    float v = errPartial[l * (NERR * 16) + t * 16];
    for (int off = 32; off > 0; off >>= 1) v += __shfl_down(v, off, 64);
    if (t == 0) errs[l] = v;
}

extern "C" void kernel_launch(void* const* d_in, const int* in_sizes, int n_in,
                              void* d_out, int out_size, void* d_ws, size_t ws_size,
                              hipStream_t stream) {
    const float* x     = (const float*)d_in[0];
    const int*   ei_nd = (const int*)d_in[2];
    const float* ea_nd = (const float*)d_in[3];
    const int*   ei    = (const int*)d_in[4];
    const float* ea    = (const float*)d_in[5];
    const float* ybus  = (const float*)d_in[6];

    float* out_f = (float*)d_out;
    float* errs  = out_f + NN;

    // workspace carve (4-byte units)
    float* wsf        = (float*)d_ws;
    float* p          = wsf;          wsf += NN;
    float* denomInv   = wsf;          wsf += NN;
    float* outA       = wsf;          wsf += NN;
    float* outB       = wsf;          wsf += NN;
    int*   cursorC_nd = (int*)wsf;    wsf += NCB;
    int*   cursorC_f  = (int*)wsf;    wsf += NCB;
    int*   cursor_nd  = (int*)wsf;    wsf += NFB;
    int*   cursor_f   = (int*)wsf;    wsf += NFB;
    float* errPartial = wsf;          wsf += (NLAYERS + 1) * NERR * 16;  // 11264
    uint2* stgC_nd    = (uint2*)wsf;  wsf += 2LL * NCB * CAPC_ND;
    uint2* stgC_f     = (uint2*)wsf;  wsf += 2LL * NCB * CAPC_F;
    uint2* stg_nd     = (uint2*)wsf;  wsf += 2LL * NFB * CAP_ND;
    uint2* stg_f      = (uint2*)wsf;  wsf += 2LL * NFB * CAP_F;

    const int* src_nd = ei_nd;
    const int* dst_nd = ei_nd + END_E;
    const int* src_f  = ei;
    const int* dst_f  = ei + EF_E;

    // ---- build phase ----
    init_kernel<<<2048, 256, 0, stream>>>(x, ybus, p, denomInv,
                                          cursorC_nd, cursorC_f, errPartial);
    binA_kernel<<<ND_TILES + F_TILES, 256, 0, stream>>>(
        src_nd, dst_nd, ea_nd, src_f, dst_f, ea,
        cursorC_nd, cursorC_f, stgC_nd, stgC_f);
    binC_kernel<<<2 * NCB, 512, 0, stream>>>(
        stgC_nd, stgC_f, cursorC_nd, cursorC_f,
        stg_nd, stg_f, cursor_nd, cursor_f);

    // ---- iterate phase ----
    out0_kernel<<<BATCH, 128, 0, stream>>>(p, denomInv, outA);
    const float* cur = outA;
    for (int k = 1; k <= NLAYERS; ++k) {
        float* nxt = (k == NLAYERS) ? out_f : ((k & 1) ? outB : outA);
        layer_kernel<true><<<NFB, 512, 0, stream>>>(
            stg_nd, stg_f, cursor_nd, cursor_f, p, denomInv, cur, nxt,
            errPartial + (long)(k - 1) * NERR * 16);
        cur = nxt;
    }
    layer_kernel<false><<<NFB, 512, 0, stream>>>(
        stg_nd, stg_f, cursor_nd, cursor_f, p, denomInv, cur, nullptr,
        errPartial + (long)NLAYERS * NERR * 16);
    err_reduce_kernel<<<NLAYERS + 1, 64, 0, stream>>>(errPartial, errs);
}